// Round 1
// baseline (467.284 us; speedup 1.0000x reference)
//
#include <hip/hip_runtime.h>
#include <hip/hip_bf16.h>

#define K_IN 2624     // 2048 + 512 + 64
#define NGATE 256
#define LDS_A_STRIDE 72   // shorts (64 + 8 pad) = 9 short8 chunks
#define SMEM_BYTES 41984  // A: 64*72*2 = 9216 ; B: 256*64*2 = 32768

typedef __attribute__((ext_vector_type(8))) short short8;
typedef __attribute__((ext_vector_type(4))) short short4_t;
typedef __attribute__((ext_vector_type(4))) float float4_t;

__device__ __forceinline__ short f2bf(float f) {
    union { __hip_bfloat16 b; short s; } u;
    u.b = __float2bfloat16(f);
    return u.s;
}

__device__ __forceinline__ float sigmoid_fast(float x) {
    return 1.f / (1.f + __expf(-x));
}

__device__ __forceinline__ float tanh_fast(float x) {
    float e = __expf(-2.f * fabsf(x));
    float t = (1.f - e) / (1.f + e);
    return copysignf(t, x);
}

// ---------------------------------------------------------------------------
// prep: Wt[n][k] = bf16(W[k][n]) for the fused weight [Wi; Wh] (K_IN x 256),
//       bsum[n] = bi[n] + bh[n]
// grid: 41 blocks (one per 64-k chunk) x 256 threads
// ---------------------------------------------------------------------------
__global__ void prep_kernel(const float* __restrict__ Wi, const float* __restrict__ bi,
                            const float* __restrict__ Wh, const float* __restrict__ bh,
                            short* __restrict__ Wt, float* __restrict__ bsum) {
    __shared__ short tile[64][256];
    const int t = threadIdx.x;
    const int kb = blockIdx.x;
    const int k0 = kb * 64;

    for (int j = 0; j < 64; ++j) {
        int k = k0 + j;
        float v = (k < 2560) ? Wi[(size_t)k * 256 + t] : Wh[(size_t)(k - 2560) * 256 + t];
        tile[j][t] = f2bf(v);
    }
    if (kb == 0) bsum[t] = bi[t] + bh[t];
    __syncthreads();

    // write transposed, k-contiguous: lane-consecutive n keeps LDS reads 2-way
    const int j0 = (t >> 6) * 16;  // wave id * 16
    for (int q = 0; q < 4; ++q) {
        int n = (t & 63) + 64 * q;
        short8 v0, v1;
#pragma unroll
        for (int jj = 0; jj < 8; ++jj) v0[jj] = tile[j0 + jj][n];
#pragma unroll
        for (int jj = 0; jj < 8; ++jj) v1[jj] = tile[j0 + 8 + jj][n];
        short* dst = Wt + (size_t)n * K_IN + k0 + j0;
        *reinterpret_cast<short8*>(dst) = v0;
        *reinterpret_cast<short8*>(dst + 8) = v1;
    }
}

// ---------------------------------------------------------------------------
// fused GEMM (bf16 MFMA) + LSTM elementwise + h@Wo reduction
// one block: 64 rows x all 256 gate cols.  256 threads = 4 waves.
// wave w owns n-cols [w*64, w*64+64).
// ---------------------------------------------------------------------------
__global__ __launch_bounds__(256, 3)
void lstm_kernel(const float* __restrict__ state, const float* __restrict__ action,
                 const float* __restrict__ hidden, const float* __restrict__ cell,
                 const short* __restrict__ Wt, const float* __restrict__ bsum,
                 const float* __restrict__ Wo, const float* __restrict__ bo,
                 float* __restrict__ out, int Brows) {
    __shared__ __align__(16) char smem[SMEM_BYTES];
    short* sA = (short*)smem;                 // [64][72] bf16 (padded)
    short* sB = (short*)(smem + 9216);        // [256][64] bf16, chunk-swizzled
    float* sG = (float*)smem;                 // epilogue: [32][260] fp32 (overlaps)

    const int t = threadIdx.x;
    const int w = t >> 6;        // wave 0..3
    const int l = t & 63;        // lane
    const int bm = blockIdx.x;   // row-tile

    // A staging: thread loads 4x float4; row = ar + p*16, cols ac..ac+3 of k-tile
    const int ar = t >> 4;            // 0..15
    const int ac = (t & 15) * 4;

    // B staging: 8 global_load_lds issues per thread; XOR chunk swizzle vs n&7
    int boff[8];
#pragma unroll
    for (int p = 0; p < 8; ++p) {
        int n = (p * 4 + w) * 8 + (l >> 3);
        int jg = (l & 7) ^ (n & 7);
        boff[p] = n * K_IN + jg * 8;   // in shorts
    }

    float4_t acc[4][4];
#pragma unroll
    for (int i = 0; i < 4; ++i)
#pragma unroll
        for (int j = 0; j < 4; ++j) acc[i][j] = (float4_t)(0.f);

    // prefetch A for iter 0 (state, k0 = 0)
    float4_t areg[4];
#pragma unroll
    for (int p = 0; p < 4; ++p) {
        size_t row = (size_t)bm * 64 + ar + p * 16;
        areg[p] = *reinterpret_cast<const float4_t*>(state + (row << 11) + ac);
    }

    for (int it = 0; it < 41; ++it) {
        const int k0 = it * 64;

        // async B tile -> LDS (L2-resident weights)
#pragma unroll
        for (int p = 0; p < 8; ++p) {
            __builtin_amdgcn_global_load_lds(
                (const __attribute__((address_space(1))) void*)(Wt + boff[p] + k0),
                (__attribute__((address_space(3))) void*)(sB + (p * 4 + w) * 512),
                16, 0, 0);
        }

        // convert prefetched A regs -> bf16 LDS
#pragma unroll
        for (int p = 0; p < 4; ++p) {
            short4_t s4;
            s4[0] = f2bf(areg[p][0]); s4[1] = f2bf(areg[p][1]);
            s4[2] = f2bf(areg[p][2]); s4[3] = f2bf(areg[p][3]);
            *reinterpret_cast<short4_t*>(sA + (ar + p * 16) * LDS_A_STRIDE + ac) = s4;
        }

        // prefetch A for next iter (virtual concat [state|action|hidden])
        if (it + 1 < 41) {
            int k1 = k0 + 64;
            const float* src; int shift; int c0;
            if (k1 < 2048)      { src = state;  shift = 11; c0 = k1; }
            else if (k1 < 2560) { src = action; shift = 9;  c0 = k1 - 2048; }
            else                { src = hidden; shift = 6;  c0 = k1 - 2560; }
#pragma unroll
            for (int p = 0; p < 4; ++p) {
                size_t row = (size_t)bm * 64 + ar + p * 16;
                areg[p] = *reinterpret_cast<const float4_t*>(src + (row << shift) + c0 + ac);
            }
        }

        __syncthreads();

        // 2 k-steps of 32, 4x4 16x16x32 MFMAs each
#pragma unroll
        for (int ks = 0; ks < 2; ++ks) {
            short8 afrag[4], bfrag[4];
#pragma unroll
            for (int mt = 0; mt < 4; ++mt) {
                int m = mt * 16 + (l & 15);
                afrag[mt] = *reinterpret_cast<short8*>(sA + m * LDS_A_STRIDE + ks * 32 + (l >> 4) * 8);
            }
#pragma unroll
            for (int nt = 0; nt < 4; ++nt) {
                int n = w * 64 + nt * 16 + (l & 15);
                int chunk = (ks * 4 + (l >> 4)) ^ (l & 7);
                bfrag[nt] = *reinterpret_cast<short8*>(sB + n * 64 + chunk * 8);
            }
#pragma unroll
            for (int mt = 0; mt < 4; ++mt)
#pragma unroll
                for (int nt = 0; nt < 4; ++nt)
                    acc[mt][nt] = __builtin_amdgcn_mfma_f32_16x16x32_bf16(
                        afrag[mt], bfrag[nt], acc[mt][nt], 0, 0, 0);
        }

        __syncthreads();
    }

    // ------------------- epilogue: LSTM + h@Wo -------------------
    float* outH = out + Brows;
    float* outC = out + Brows + (size_t)Brows * 64;
    const float wo = Wo[l];
    const float bov = bo[0];
    const float b0 = bsum[l];
    const float b1 = bsum[64 + l];
    const float b2 = bsum[128 + l];
    const float b3 = bsum[192 + l];

#pragma unroll
    for (int ph = 0; ph < 2; ++ph) {
        // dump this phase's 32 gate-rows to LDS (C-layout: row=(l>>4)*4+reg, col=l&15)
#pragma unroll
        for (int mh = 0; mh < 2; ++mh) {
            int mt = ph * 2 + mh;
#pragma unroll
            for (int nt = 0; nt < 4; ++nt) {
#pragma unroll
                for (int r = 0; r < 4; ++r) {
                    int row = mh * 16 + (l >> 4) * 4 + r;
                    int col = w * 64 + nt * 16 + (l & 15);
                    sG[row * 260 + col] = acc[mt][nt][r];
                }
            }
        }
        __syncthreads();

        // wave w handles rows w*8 .. w*8+7 ; lane = hidden index
#pragma unroll
        for (int q = 0; q < 8; ++q) {
            int rr = w * 8 + q;
            size_t gr = (size_t)bm * 64 + ph * 32 + rr;
            float gi = sG[rr * 260 + l]       + b0;
            float gf = sG[rr * 260 + 64 + l]  + b1;
            float gg = sG[rr * 260 + 128 + l] + b2;
            float go = sG[rr * 260 + 192 + l] + b3;
            float i_t = sigmoid_fast(gi);
            float f_t = sigmoid_fast(gf);
            float g_t = tanh_fast(gg);
            float o_t = sigmoid_fast(go);
            float c_old = cell[gr * 64 + l];
            float c_t = f_t * c_old + i_t * g_t;
            float h_t = o_t * tanh_fast(c_t);
            outC[gr * 64 + l] = c_t;
            outH[gr * 64 + l] = h_t;
            float v = h_t * wo;
#pragma unroll
            for (int off = 32; off > 0; off >>= 1) v += __shfl_down(v, off);
            if (l == 0) out[gr] = tanh_fast(v + bov);
        }
        __syncthreads();
    }
}

extern "C" void kernel_launch(void* const* d_in, const int* in_sizes, int n_in,
                              void* d_out, int out_size, void* d_ws, size_t ws_size,
                              hipStream_t stream) {
    const float* state  = (const float*)d_in[0];
    const float* action = (const float*)d_in[1];
    const float* hidden = (const float*)d_in[2];
    const float* cell   = (const float*)d_in[3];
    const float* Wi     = (const float*)d_in[4];
    const float* bi     = (const float*)d_in[5];
    const float* Wh     = (const float*)d_in[6];
    const float* bh     = (const float*)d_in[7];
    const float* Wo     = (const float*)d_in[8];
    const float* bo     = (const float*)d_in[9];

    const int Brows = in_sizes[0] / 2048;   // 32768

    short* Wt   = (short*)d_ws;                                   // 256 x 2624 bf16
    float* bsum = (float*)((char*)d_ws + (size_t)NGATE * K_IN * sizeof(short));

    prep_kernel<<<K_IN / 64, 256, 0, stream>>>(Wi, bi, Wh, bh, Wt, bsum);
    lstm_kernel<<<Brows / 64, 256, 0, stream>>>(state, action, hidden, cell,
                                                Wt, bsum, Wo, bo, (float*)d_out, Brows);
}